// Round 1
// baseline (135.087 us; speedup 1.0000x reference)
//
#include <hip/hip_runtime.h>
#include <hip/hip_bf16.h>
#include <stdint.h>

typedef __attribute__((ext_vector_type(8))) short short8;
typedef __attribute__((ext_vector_type(4))) float float4_t;

#define DDIM 128
#define TMAX 2048

__device__ inline unsigned short f32_to_bf16_rne(float f) {
    uint32_t u = __float_as_uint(f);
    uint32_t r = (u + 0x7FFFu + ((u >> 16) & 1u)) >> 16;
    return (unsigned short)r;
}

// Rotate k: FWHT-128 per row, scale 128^-0.5, round to bf16 (matches reference
// _rotate_activation which casts back to bf16).
__global__ __launch_bounds__(DDIM) void rotate_k_kernel(
        const unsigned short* __restrict__ k, unsigned short* __restrict__ kr, int T) {
    __shared__ float buf[DDIM];
    int row = blockIdx.x;
    int d = threadIdx.x;
    buf[d] = __uint_as_float(((uint32_t)k[(size_t)row * DDIM + d]) << 16);
    __syncthreads();
    for (int bit = 1; bit < DDIM; bit <<= 1) {
        float a = buf[d];
        float b = buf[d ^ bit];
        float v = (d & bit) ? (b - a) : (a + b);
        __syncthreads();
        buf[d] = v;
        __syncthreads();
    }
    kr[(size_t)row * DDIM + d] = f32_to_bf16_rne(buf[d] * 0.08838834764831845f);
}

// One block per token t: rotate q[t], MFMA scores vs all valid kv positions,
// exact radix-select top-K, bitonic sort, emit (vals, idx-as-float).
__global__ __launch_bounds__(256) void indexer_main(
        const unsigned short* __restrict__ q,   // [T,H,128] bf16 bits
        const float* __restrict__ w,            // [T,H]
        const int* __restrict__ seq_lens, int n_seq,
        const unsigned short* __restrict__ kr,  // [T,128] bf16 bits (rotated)
        float* __restrict__ out_vals,           // [T,K]
        float* __restrict__ out_idx,            // [T,K] (float-encoded ints)
        int T, int H, int K) {
    __shared__ float rotF[16 * DDIM];                    // 8KB
    __shared__ __align__(16) unsigned short qbf[16 * DDIM]; // 4KB
    __shared__ float scoresL[TMAX];                      // 8KB
    __shared__ unsigned long long cand[TMAX];            // 16KB
    __shared__ uint32_t hist[256];                       // 1KB
    __shared__ int sh_ks, sh_cnt, sh_j, sh_hi;

    const int t   = blockIdx.x;
    const int tid = threadIdx.x;

    if (tid == 0) {
        int off = 0, ks0 = 0;
        for (int i = 0; i < n_seq; ++i) {
            int nx = off + seq_lens[i];
            if (t < nx) { ks0 = off; break; }
            off = nx;
        }
        sh_ks = ks0;
        sh_cnt = 0;
    }

    // ---- load q[t] (H*128 bf16) to f32 LDS ----
    for (int e = 0; e < (16 * DDIM) / 256; ++e) {
        int i = tid + 256 * e;
        rotF[i] = __uint_as_float(((uint32_t)q[(size_t)t * H * DDIM + i]) << 16);
    }
    __syncthreads();

    // ---- FWHT over last dim (7 stages; i^bit stays within the same head row) ----
    for (int bit = 1; bit < DDIM; bit <<= 1) {
        float nv[8];
        for (int e = 0; e < 8; ++e) {
            int i = tid + 256 * e;
            float a = rotF[i], b = rotF[i ^ bit];
            nv[e] = (i & bit) ? (b - a) : (a + b);
        }
        __syncthreads();
        for (int e = 0; e < 8; ++e) rotF[tid + 256 * e] = nv[e];
        __syncthreads();
    }
    for (int e = 0; e < 8; ++e) {
        int i = tid + 256 * e;
        qbf[i] = f32_to_bf16_rne(rotF[i] * 0.08838834764831845f);
    }
    __syncthreads();

    const int ks = sh_ks;
    const int ke = t + 1;
    const int n  = ke - ks;

    // ---- MFMA score phase ----
    const int lane = tid & 63;
    const int wv   = tid >> 6;
    const int col  = lane & 15;   // A row m / B col n / D col n
    const int kgrp = lane >> 4;

    short8 afrag[4];
    for (int kk = 0; kk < 4; ++kk)
        afrag[kk] = *(const short8*)&qbf[col * DDIM + kk * 32 + kgrp * 8];
    float w4[4];
    for (int r = 0; r < 4; ++r)
        w4[r] = w[(size_t)t * H + kgrp * 4 + r];

    const int ntiles = (n + 15) >> 4;
    for (int tile = wv; tile < ntiles; tile += 4) {
        int s0 = ks + tile * 16;
        int srow = s0 + col;
        if (srow >= T) srow = 0;  // clamp OOB tail; masked below
        const unsigned short* kbase = kr + (size_t)srow * DDIM + kgrp * 8;
        float4_t acc = {0.f, 0.f, 0.f, 0.f};
        for (int kk = 0; kk < 4; ++kk) {
            short8 bfrag = *(const short8*)(kbase + kk * 32);
            acc = __builtin_amdgcn_mfma_f32_16x16x32_bf16(afrag[kk], bfrag, acc, 0, 0, 0);
        }
        float p = 0.f;
        for (int r = 0; r < 4; ++r) {
            float v = acc[r];
            v = v > 0.f ? v : 0.f;
            p += w4[r] * v;
        }
        p += __shfl_xor(p, 16, 64);
        p += __shfl_xor(p, 32, 64);
        if (lane < 16) {
            int s = s0 + lane;
            if (s < ke) scoresL[s] = p;
        }
    }
    __syncthreads();

    // ---- exact top-K selection ----
    const int Keff = (n < K) ? n : K;
    uint32_t vstar = 0;
    if (n > K) {
        uint32_t prefix = 0;
        int Kr = K;
        for (int b = 3; b >= 0; --b) {
            hist[tid] = 0;
            __syncthreads();
            uint32_t maskhi = (b == 3) ? 0u : (0xFFFFFFFFu << ((b + 1) * 8));
            for (int s = ks + tid; s < ke; s += 256) {
                uint32_t u = __float_as_uint(scoresL[s]);
                if ((u & maskhi) == (prefix & maskhi))
                    atomicAdd(&hist[(u >> (b * 8)) & 0xFFu], 1u);
            }
            __syncthreads();
            // inclusive suffix scan of hist
            for (int offd = 1; offd < 256; offd <<= 1) {
                uint32_t v = hist[tid] + ((tid + offd) < 256 ? hist[tid + offd] : 0u);
                __syncthreads();
                hist[tid] = v;
                __syncthreads();
            }
            uint32_t c  = hist[tid];
            uint32_t cn = (tid < 255) ? hist[tid + 1] : 0u;
            if ((int)c >= Kr && (int)cn < Kr) { sh_j = tid; sh_hi = (int)cn; }
            __syncthreads();
            prefix |= ((uint32_t)sh_j) << (b * 8);
            Kr -= sh_hi;
            __syncthreads();
        }
        vstar = prefix;
    }

    // gather candidates >= vstar as 64-bit keys (val desc, idx asc tie-break)
    for (int s = ks + tid; s < ke; s += 256) {
        uint32_t u = __float_as_uint(scoresL[s]);
        if (u >= vstar) {
            int pos = atomicAdd(&sh_cnt, 1);
            cand[pos] = ((unsigned long long)u << 32) | (uint32_t)(~s);
        }
    }
    __syncthreads();
    const int cnt = sh_cnt;
    int P = 1;
    while (P < cnt) P <<= 1;
    for (int i = cnt + tid; i < P; i += 256) cand[i] = 0ull;
    __syncthreads();

    // bitonic sort descending on 64-bit keys
    for (int size = 2; size <= P; size <<= 1) {
        for (int stride = size >> 1; stride >= 1; stride >>= 1) {
            for (int i = tid; i < P; i += 256) {
                int j = i ^ stride;
                if (j > i) {
                    unsigned long long a = cand[i], b = cand[j];
                    bool desc = ((i & size) == 0);
                    if (desc ? (a < b) : (a > b)) { cand[i] = b; cand[j] = a; }
                }
            }
            __syncthreads();
        }
    }

    // ---- emit ----
    for (int r = tid; r < K; r += 256) {
        float v; int idx;
        if (r < Keff) {
            unsigned long long key = cand[r];
            v = __uint_as_float((uint32_t)(key >> 32));
            idx = (int)(~((uint32_t)key));
        } else {
            int pidx = r - Keff;
            idx = (pidx < ks) ? pidx : (ke + (pidx - ks));
            v = -1e30f;
        }
        out_vals[(size_t)t * K + r] = v;
        out_idx[(size_t)t * K + r]  = (float)idx;
    }
}

extern "C" void kernel_launch(void* const* d_in, const int* in_sizes, int n_in,
                              void* d_out, int out_size, void* d_ws, size_t ws_size,
                              hipStream_t stream) {
    const unsigned short* q = (const unsigned short*)d_in[0];
    const unsigned short* k = (const unsigned short*)d_in[1];
    const float* w          = (const float*)d_in[2];
    const int* seq_lens     = (const int*)d_in[3];
    const int n_seq = in_sizes[3];
    const int T = in_sizes[1] / DDIM;      // k is [T, 128]
    const int H = in_sizes[2] / T;         // weights [T, H]
    const int K = out_size / (2 * T);      // d_out = vals [T,K] ++ idx [T,K]

    unsigned short* kr = (unsigned short*)d_ws;   // rotated k, bf16 bits
    float* out_vals = (float*)d_out;
    float* out_idx  = out_vals + (size_t)T * K;

    rotate_k_kernel<<<dim3(T), dim3(DDIM), 0, stream>>>(k, kr, T);
    indexer_main<<<dim3(T), dim3(256), 0, stream>>>(
        q, w, seq_lens, n_seq, kr, out_vals, out_idx, T, H, K);
}

// Round 2
// 131.517 us; speedup vs baseline: 1.0271x; 1.0271x over previous
//
#include <hip/hip_runtime.h>
#include <hip/hip_bf16.h>
#include <stdint.h>

typedef __attribute__((ext_vector_type(8))) short short8;
typedef __attribute__((ext_vector_type(4))) float float4_t;

#define DDIM 128
#define SORTN 256
#define TCAP 2048   // max packed tokens supported (input: T=2048)

__device__ inline unsigned short f32_to_bf16_rne(float f) {
    uint32_t u = __float_as_uint(f);
    return (unsigned short)((u + 0x7FFFu + ((u >> 16) & 1u)) >> 16);
}
__device__ inline float bf16_to_f32(unsigned short h) {
    return __uint_as_float(((uint32_t)h) << 16);
}

// ---- rotate k: one wave per row, FWHT-128 via registers + shfl, no LDS ----
__global__ __launch_bounds__(256) void rotate_k_kernel(
        const unsigned short* __restrict__ k, unsigned short* __restrict__ kr, int T) {
    int row = blockIdx.x * 4 + (threadIdx.x >> 6);
    if (row >= T) return;
    int lane = threadIdx.x & 63;
    ushort2 in = *(const ushort2*)(k + (size_t)row * DDIM + 2 * lane);
    float x0 = bf16_to_f32(in.x), x1 = bf16_to_f32(in.y);
    { float a = x0 + x1, b = x0 - x1; x0 = a; x1 = b; }   // bit 1 (in-reg)
    #pragma unroll
    for (int m = 1; m <= 32; m <<= 1) {                    // bits 2..64 via xor-lanes
        float y0 = __shfl_xor(x0, m, 64);
        float y1 = __shfl_xor(x1, m, 64);
        bool hi = (lane & m) != 0;
        x0 = hi ? (y0 - x0) : (x0 + y0);
        x1 = hi ? (y1 - x1) : (x1 + y1);
    }
    const float sc = 0.08838834764831845f;
    ushort2 o; o.x = f32_to_bf16_rne(x0 * sc); o.y = f32_to_bf16_rne(x1 * sc);
    *(ushort2*)(kr + (size_t)row * DDIM + 2 * lane) = o;
}

__device__ inline void do_tile(int s0, int ke, int ks, int T, int lane, int col, int kgrp,
                               const unsigned short* __restrict__ kr,
                               const short8* afrag, const float* w4,
                               float* scoresL) {
    int sa = s0 + col; if (sa >= T) sa = T - 1;            // clamp pad rows (masked below)
    const short8* kb = (const short8*)(kr + (size_t)sa * DDIM + kgrp * 8);
    float4_t acc = {0.f, 0.f, 0.f, 0.f};
    acc = __builtin_amdgcn_mfma_f32_16x16x32_bf16(afrag[0], kb[0],  acc, 0, 0, 0);
    acc = __builtin_amdgcn_mfma_f32_16x16x32_bf16(afrag[1], kb[4],  acc, 0, 0, 0);
    acc = __builtin_amdgcn_mfma_f32_16x16x32_bf16(afrag[2], kb[8],  acc, 0, 0, 0);
    acc = __builtin_amdgcn_mfma_f32_16x16x32_bf16(afrag[3], kb[12], acc, 0, 0, 0);
    float p = 0.f;
    #pragma unroll
    for (int r = 0; r < 4; ++r) { float v = acc[r]; v = v > 0.f ? v : 0.f; p += w4[r] * v; }
    p += __shfl_xor(p, 16, 64);
    p += __shfl_xor(p, 32, 64);
    if (lane < 16) { int s = s0 + lane; if (s < ke) scoresL[s - ks] = p; }
}

// one wave (64 threads) per token
__global__ __launch_bounds__(64, 4) void indexer_main(
        const unsigned short* __restrict__ q,   // [T,H,128] bf16 bits
        const float* __restrict__ w,            // [T,H]
        const int* __restrict__ seq_lens, int n_seq,
        const unsigned short* __restrict__ kr,  // [T,128] rotated bf16 bits
        float* __restrict__ out_vals, float* __restrict__ out_idx,
        int T, int H, int K) {
    __shared__ float scoresL[TCAP];                 // 8 KB
    __shared__ uint32_t hist[256];                  // 1 KB
    __shared__ unsigned long long cand[SORTN];      // 2 KB

    const int t    = T - 1 - blockIdx.x;            // big-n tokens first
    const int lane = threadIdx.x;
    const int col  = lane & 15;
    const int kgrp = lane >> 4;

    // seq bounds (uniform)
    int ks = 0;
    { int off = 0;
      for (int i = 0; i < n_seq; ++i) { int nx = off + seq_lens[i]; if (t < nx) { ks = off; break; } off = nx; } }
    const int ke = t + 1;
    const int n  = ke - ks;

    // ---- rotate q[t] in registers: f[kk][j] = qrow[col][kk*32 + kgrp*8 + j] ----
    float f[4][8];
    const unsigned short* qrow = q + ((size_t)t * H + col) * DDIM + kgrp * 8;
    #pragma unroll
    for (int kk = 0; kk < 4; ++kk) {
        short8 v = *(const short8*)(qrow + kk * 32);
        #pragma unroll
        for (int j = 0; j < 8; ++j) f[kk][j] = bf16_to_f32((unsigned short)v[j]);
    }
    // bits 1,2,4 within j
    #pragma unroll
    for (int b = 1; b <= 4; b <<= 1)
        #pragma unroll
        for (int kk = 0; kk < 4; ++kk)
            #pragma unroll
            for (int j = 0; j < 8; ++j)
                if (!(j & b)) { float a = f[kk][j], c = f[kk][j | b];
                                f[kk][j] = a + c; f[kk][j | b] = a - c; }
    // bit 8: kgrp bit0 -> lane^16 ; bit 16: kgrp bit1 -> lane^32
    #pragma unroll
    for (int kk = 0; kk < 4; ++kk)
        #pragma unroll
        for (int j = 0; j < 8; ++j) {
            float o = __shfl_xor(f[kk][j], 16, 64);
            f[kk][j] = (kgrp & 1) ? (o - f[kk][j]) : (f[kk][j] + o);
        }
    #pragma unroll
    for (int kk = 0; kk < 4; ++kk)
        #pragma unroll
        for (int j = 0; j < 8; ++j) {
            float o = __shfl_xor(f[kk][j], 32, 64);
            f[kk][j] = (kgrp & 2) ? (o - f[kk][j]) : (f[kk][j] + o);
        }
    // bit 32: kk^1 ; bit 64: kk^2 (in-reg)
    #pragma unroll
    for (int j = 0; j < 8; ++j) {
        { float a = f[0][j], c = f[1][j]; f[0][j] = a + c; f[1][j] = a - c; }
        { float a = f[2][j], c = f[3][j]; f[2][j] = a + c; f[3][j] = a - c; }
        { float a = f[0][j], c = f[2][j]; f[0][j] = a + c; f[2][j] = a - c; }
        { float a = f[1][j], c = f[3][j]; f[1][j] = a + c; f[3][j] = a - c; }
    }
    short8 afrag[4];
    const float sc = 0.08838834764831845f;
    #pragma unroll
    for (int kk = 0; kk < 4; ++kk)
        #pragma unroll
        for (int j = 0; j < 8; ++j)
            afrag[kk][j] = (short)f32_to_bf16_rne(f[kk][j] * sc);

    float w4[4];
    #pragma unroll
    for (int r = 0; r < 4; ++r) w4[r] = w[(size_t)t * H + kgrp * 4 + r];

    // ---- MFMA scores over [ks, ke), 2-tile ILP ----
    const int ntiles = (n + 15) >> 4;
    const int ntiles2 = (ntiles + 1) & ~1;
    for (int tile = 0; tile < ntiles2; tile += 2) {
        do_tile(ks + tile * 16,       ke, ks, T, lane, col, kgrp, kr, afrag, w4, scoresL);
        do_tile(ks + (tile + 1) * 16, ke, ks, T, lane, col, kgrp, kr, afrag, w4, scoresL);
    }
    __syncthreads();

    // ---- exact radix-select on 44-bit key = ((u<<11)|(2047-s))+1 ----
    const int Keff = (n < K) ? n : K;
    unsigned long long kstar = 1ull;   // n<=K: take everything
    if (n > K) {
        unsigned long long pref = 0;
        int Kr = K;
        for (int pass = 0; pass < 6; ++pass) {
            const int shift = 40 - 8 * pass;
            hist[lane] = 0; hist[lane + 64] = 0; hist[lane + 128] = 0; hist[lane + 192] = 0;
            __syncthreads();
            const unsigned long long phi = pref >> (shift + 8);
            for (int i = lane; i < n; i += 64) {
                unsigned long long key =
                    (((unsigned long long)__float_as_uint(scoresL[i]) << 11) |
                     (unsigned long long)(2047 - (ks + i))) + 1ull;
                if ((key >> (shift + 8)) == phi)
                    atomicAdd(&hist[(unsigned)(key >> shift) & 255u], 1u);
            }
            __syncthreads();
            uint32_t h0 = hist[4 * lane], h1 = hist[4 * lane + 1],
                     h2 = hist[4 * lane + 2], h3 = hist[4 * lane + 3];
            uint32_t c3 = h3, c2 = h2 + c3, c1 = h1 + c2, c0 = h0 + c1;
            uint32_t tot = c0, inc = tot;
            #pragma unroll
            for (int off = 1; off < 64; off <<= 1) {
                uint32_t v = __shfl_down(inc, off, 64);
                if (lane + off < 64) inc += v;
            }
            uint32_t sfx = inc - tot;   // sum over lanes > lane
            uint32_t cg0 = sfx + c0, cg1 = sfx + c1, cg2 = sfx + c2, cg3 = sfx + c3, cg4 = sfx;
            int fi = -1; uint32_t fhi = 0;
            uint32_t KrU = (uint32_t)Kr;
            if      (cg0 >= KrU && cg1 < KrU) { fi = 0; fhi = cg1; }
            else if (cg1 >= KrU && cg2 < KrU) { fi = 1; fhi = cg2; }
            else if (cg2 >= KrU && cg3 < KrU) { fi = 2; fhi = cg3; }
            else if (cg3 >= KrU && cg4 < KrU) { fi = 3; fhi = cg4; }
            unsigned long long mask = __ballot(fi >= 0);
            int src = __ffsll((long long)mask) - 1;
            int digit  = __shfl(4 * lane + fi, src, 64);
            int hiv    = __shfl((int)fhi, src, 64);
            pref |= ((unsigned long long)digit) << shift;
            Kr -= hiv;
            __syncthreads();
        }
        kstar = pref;
    }

    // ---- gather exactly Keff keys >= kstar (ballot compaction) ----
    {
        int base = 0;
        for (int i = lane; i < n; i += 64) {
            unsigned long long key =
                (((unsigned long long)__float_as_uint(scoresL[i]) << 11) |
                 (unsigned long long)(2047 - (ks + i))) + 1ull;
            bool pred = (key >= kstar);
            unsigned long long m = __ballot(pred);
            if (pred) {
                int pos = base + __popcll(m & ((1ull << lane) - 1ull));
                if (pos < SORTN) cand[pos] = key;
            }
            base += __popcll(m);
        }
        for (int i = Keff + lane; i < SORTN; i += 64) cand[i] = 0ull;
    }
    __syncthreads();

    // ---- register bitonic sort of 256 keys, descending; e = 4*lane + r ----
    unsigned long long kreg[4];
    #pragma unroll
    for (int r = 0; r < 4; ++r) kreg[r] = cand[4 * lane + r];

    #define CX(a, b, dsc) { unsigned long long _mx = (a) > (b) ? (a) : (b); \
                            unsigned long long _mn = (a) > (b) ? (b) : (a); \
                            (a) = (dsc) ? _mx : _mn; (b) = (dsc) ? _mn : _mx; }
    #pragma unroll
    for (int size = 2; size <= SORTN; size <<= 1) {
        #pragma unroll
        for (int stride = SORTN >> 1; stride >= 4; stride >>= 1) {
            if (stride < size || (size == SORTN && stride <= size)) {
                if (stride <= (size >> 1) || size == SORTN) {
                    // active when stride <= size/2
                }
            }
            if (stride > (size >> 1)) continue;
            int lmask = stride >> 2;
            #pragma unroll
            for (int r = 0; r < 4; ++r) {
                int e = 4 * lane + r;
                unsigned long long other = __shfl_xor(kreg[r], lmask, 64);
                bool desc = ((e & size) == 0);
                bool iAmLow = ((e & stride) == 0);
                bool keepMax = (iAmLow == desc);
                kreg[r] = keepMax ? (kreg[r] > other ? kreg[r] : other)
                                  : (kreg[r] < other ? kreg[r] : other);
            }
        }
        if (size >= 4) {
            bool d = (((4 * lane) & size) == 0);
            CX(kreg[0], kreg[2], d);
            CX(kreg[1], kreg[3], d);
            CX(kreg[0], kreg[1], d);
            CX(kreg[2], kreg[3], d);
        } else {
            CX(kreg[0], kreg[1], true);
            CX(kreg[2], kreg[3], false);
        }
    }
    #undef CX

    // ---- emit (val f32, idx as float), 16B stores ----
    float4_t v4, i4;
    #pragma unroll
    for (int r = 0; r < 4; ++r) {
        int e = 4 * lane + r;
        unsigned long long key = kreg[r];
        float v; int idx;
        if (key != 0ull) {
            unsigned long long km1 = key - 1ull;
            v = __uint_as_float((uint32_t)(km1 >> 11));
            idx = 2047 - (int)(km1 & 0x7FFull);
        } else {
            int pidx = e - Keff;
            idx = (pidx < ks) ? pidx : (ke + (pidx - ks));
            v = -1e30f;
        }
        v4[r] = v; i4[r] = (float)idx;
    }
    if (4 * lane < K) {
        *(float4_t*)(out_vals + (size_t)t * K + 4 * lane) = v4;
        *(float4_t*)(out_idx  + (size_t)t * K + 4 * lane) = i4;
    }
}

extern "C" void kernel_launch(void* const* d_in, const int* in_sizes, int n_in,
                              void* d_out, int out_size, void* d_ws, size_t ws_size,
                              hipStream_t stream) {
    const unsigned short* q = (const unsigned short*)d_in[0];
    const unsigned short* k = (const unsigned short*)d_in[1];
    const float* w          = (const float*)d_in[2];
    const int* seq_lens     = (const int*)d_in[3];
    const int n_seq = in_sizes[3];
    const int T = in_sizes[1] / DDIM;
    const int H = in_sizes[2] / T;
    const int K = out_size / (2 * T);

    unsigned short* kr = (unsigned short*)d_ws;      // [T,128] rotated k
    float* out_vals = (float*)d_out;
    float* out_idx  = out_vals + (size_t)T * K;

    rotate_k_kernel<<<dim3((T + 3) / 4), dim3(256), 0, stream>>>(k, kr, T);
    indexer_main<<<dim3(T), dim3(64), 0, stream>>>(
        q, w, seq_lens, n_seq, kr, out_vals, out_idx, T, H, K);
}